// Round 11
// baseline (201.192 us; speedup 1.0000x reference)
//
#include <hip/hip_runtime.h>
#include <stdint.h>
#include <stddef.h>

#define EMB 1024
#define NTOK 16384

typedef __attribute__((ext_vector_type(8))) short short8;
typedef __attribute__((ext_vector_type(4))) float floatx4;

__device__ __forceinline__ unsigned short f2bf(float f) {
    union { float f; unsigned int u; } v; v.f = f;
    unsigned int u = v.u;
    unsigned int r = (u + 0x7fffu + ((u >> 16) & 1u)) >> 16;
    return (unsigned short)r;
}
__device__ __forceinline__ float bf2f(unsigned short s) {
    union { unsigned int u; float f; } v; v.u = ((unsigned int)s) << 16;
    return v.f;
}

__device__ __forceinline__ void gload16(const void* g, void* l) {
    __builtin_amdgcn_global_load_lds(
        (const __attribute__((address_space(1))) void*)g,
        (__attribute__((address_space(3))) void*)l, 16, 0, 0);
}

// ---------------- fp32 -> bf16 conversion ----------------
__global__ void cvt_kernel(const float* __restrict__ in,
                           unsigned short* __restrict__ out, int n4) {
    int idx = blockIdx.x * blockDim.x + threadIdx.x;
    int stride = gridDim.x * blockDim.x;
    for (int i = idx; i < n4; i += stride) {
        float4 f = reinterpret_cast<const float4*>(in)[i];
        ushort4 o;
        o.x = f2bf(f.x); o.y = f2bf(f.y); o.z = f2bf(f.z); o.w = f2bf(f.w);
        reinterpret_cast<ushort4*>(out)[i] = o;
    }
}

__global__ void cvt4_kernel(const float* __restrict__ s0, const float* __restrict__ s1,
                            const float* __restrict__ s2, const float* __restrict__ s3,
                            unsigned short* __restrict__ out) {
    int idx = blockIdx.x * blockDim.x + threadIdx.x;
    const int total = 4 << 18;
    int stride = gridDim.x * blockDim.x;
    for (int i = idx; i < total; i += stride) {
        int w = i >> 18, r = i & ((1 << 18) - 1);
        const float* s = (w == 0) ? s0 : (w == 1) ? s1 : (w == 2) ? s2 : s3;
        float4 f = reinterpret_cast<const float4*>(s)[r];
        ushort4 o;
        o.x = f2bf(f.x); o.y = f2bf(f.y); o.z = f2bf(f.z); o.w = f2bf(f.w);
        reinterpret_cast<ushort4*>(out)[i] = o;
    }
}

__global__ void bias_cat_kernel(const float* __restrict__ b0,
                                const float* __restrict__ b1,
                                const float* __restrict__ b2,
                                float* __restrict__ out) {
    int i = blockIdx.x * blockDim.x + threadIdx.x;
    float v = (i < 1024) ? b0[i] : (i < 2048 ? b1[i - 1024] : b2[i - 2048]);
    out[i] = v;
}

// ------- 256x256 bf16 GEMM, persistent multi-n blocks, K=1024 hardcoded -------
// Internals = r5's proven gemm256 (BK=64, 512 thr 8 waves 2Mx4N, 128 KB dbuf LDS,
// XOR-swizzled granules, 2 counted-vmcnt sync points per K-tile). New: each block
// fixes its m-tile and sweeps nt_n n-tiles as ONE continuous 16*nt_n-tile pipeline;
// per-n acc dump is inlined (stores drain under the next n-tile's MFMA). Removes
// 2/3 of per-block prologue/warmup/epilogue dead time for QKV (grid = 1 block/CU).
__device__ __forceinline__ void store_val(float* C, size_t idx, float v) { C[idx] = v; }
__device__ __forceinline__ void store_val(unsigned short* C, size_t idx, float v) { C[idx] = f2bf(v); }

template<typename OUT_T>
__global__ __launch_bounds__(512, 1)
void gemm256mn(const unsigned short* __restrict__ A,
               const unsigned short* __restrict__ B,
               const float* __restrict__ bias,
               OUT_T* __restrict__ C,
               int Nc, int nt_n)
{
    __shared__ unsigned short lds[65536];  // 128 KB
    const int K = 1024;                    // hardcoded: all GEMMs here have K=1024
    const int NT = 16;                     // K / 64

    // XCD mapping: x = XCD; 8 m-tiles per XCD; ngrp picks the n-tile group.
    const int bid = blockIdx.x;            // grid = 256 = 8 XCD * 8 m * 4 ngrp
    const int x = bid & 7;
    const int w = bid >> 3;
    const int m0 = (x * 8 + (w & 7)) * 256;
    const int n_base = (w >> 3) * nt_n * 256;

    const int tid  = threadIdx.x;
    const int lane = tid & 63;
    const int wid  = tid >> 6;
    const int wm = (wid >> 2) * 128;
    const int wn = (wid & 3) * 64;
    const int rr = lane & 15;
    const int klo = (((lane >> 4) ^ ((rr >> 1) & 3)) << 3);

    const int aro = (wm + rr) * 32 + klo;
    const int bro = 16384 + (wn + rr) * 32 + klo;

    const unsigned short* pA[2];
    const unsigned short* pB[2];   // n_base panel, nb=0
    int ldst[2];
#pragma unroll
    for (int l = 0; l < 2; ++l) {
        const int P16  = l * 512 + tid;
        const int rowS = P16 >> 2;
        const int colel = (((P16 & 3) ^ ((rowS >> 1) & 3)) << 3);
        pA[l] = A + (size_t)(m0 + rowS) * K + colel;
        pB[l] = B + (size_t)(n_base + rowS) * K + colel;
        ldst[l] = P16 * 8;
    }
    const size_t nstep = (size_t)256 * K;  // elements per n-tile B panel

    floatx4 acc[8][4];
#pragma unroll
    for (int i = 0; i < 8; ++i)
#pragma unroll
        for (int j = 0; j < 4; ++j)
            acc[i][j] = (floatx4){0.f, 0.f, 0.f, 0.f};

    const int TOT = nt_n * NT;

    // ---- prologue: stage vt=0 into buf0, drain, read kh0 frags ----
#pragma unroll
    for (int l = 0; l < 2; ++l) {
        gload16(pA[l],      &lds[0     + ldst[l]]);
        gload16(pA[l] + 32, &lds[8192  + ldst[l]]);
        gload16(pB[l],      &lds[16384 + ldst[l]]);
        gload16(pB[l] + 32, &lds[24576 + ldst[l]]);
    }
    asm volatile("s_waitcnt vmcnt(0)" ::: "memory");
    asm volatile("s_barrier" ::: "memory");

    short8 a0[4], a1[4], b0[4];
#pragma unroll
    for (int i = 0; i < 4; ++i)
        a0[i] = *reinterpret_cast<const short8*>(&lds[aro + i * 512]);
#pragma unroll
    for (int j = 0; j < 4; ++j)
        b0[j] = *reinterpret_cast<const short8*>(&lds[bro + j * 512]);

    const int cn  = lane & 15;
    const int cm4 = (lane >> 4) * 4;

    for (int vt = 0; vt < TOT; ++vt) {
        const int cur = (vt & 1) * 32768;
        const int nxt = cur ^ 32768;
        int vtn = vt + 1; if (vtn == TOT) vtn = 0;      // harmless wrap stage
        const int ktn = (vtn & 15) * 64;
        const int nbn = vtn >> 4;
        const unsigned short* pBn0 = pB[0] + (size_t)nbn * nstep + ktn;
        const unsigned short* pBn1 = pB[1] + (size_t)nbn * nstep + ktn;

        // ============ region 1: kh0 (a0,b0 already in regs) ============
        gload16(pA[0] + ktn, &lds[nxt + ldst[0]]);           // R0 = A-kh0(next)
        gload16(pA[1] + ktn, &lds[nxt + ldst[1]]);
        gload16(pBn0,        &lds[nxt + 16384 + ldst[0]]);   // R1 = B-kh0(next)
        gload16(pBn1,        &lds[nxt + 16384 + ldst[1]]);
#pragma unroll
        for (int i = 0; i < 4; ++i)                          // rh1 of kh0
            a1[i] = *reinterpret_cast<const short8*>(&lds[cur + aro + 2048 + i * 512]);
        __builtin_amdgcn_s_setprio(1);
#pragma unroll
        for (int j = 0; j < 4; ++j)
#pragma unroll
            for (int i = 0; i < 4; ++i)
                acc[i][j] = __builtin_amdgcn_mfma_f32_16x16x32_bf16(a0[i], b0[j], acc[i][j], 0, 0, 0);
#pragma unroll
        for (int j = 0; j < 4; ++j)
#pragma unroll
            for (int i = 0; i < 4; ++i)
                acc[4 + i][j] = __builtin_amdgcn_mfma_f32_16x16x32_bf16(a1[i], b0[j], acc[4 + i][j], 0, 0, 0);
        __builtin_amdgcn_s_setprio(0);
        // drain prev tile's R2,R3 (this tile's kh1 regions); leaves R0,R1 in flight
        asm volatile("s_waitcnt vmcnt(4)" ::: "memory");
        asm volatile("s_barrier" ::: "memory");

        // ============ region 2: kh1 ============
        gload16(pA[0] + ktn + 32, &lds[nxt + 8192 + ldst[0]]);   // R2 = A-kh1(next)
        gload16(pA[1] + ktn + 32, &lds[nxt + 8192 + ldst[1]]);
        gload16(pBn0 + 32,        &lds[nxt + 24576 + ldst[0]]);  // R3 = B-kh1(next)
        gload16(pBn1 + 32,        &lds[nxt + 24576 + ldst[1]]);
#pragma unroll
        for (int i = 0; i < 4; ++i)
            a0[i] = *reinterpret_cast<const short8*>(&lds[cur + 8192 + aro + i * 512]);
#pragma unroll
        for (int j = 0; j < 4; ++j)
            b0[j] = *reinterpret_cast<const short8*>(&lds[cur + 8192 + bro + j * 512]);
#pragma unroll
        for (int i = 0; i < 4; ++i)
            a1[i] = *reinterpret_cast<const short8*>(&lds[cur + 8192 + aro + 2048 + i * 512]);
        __builtin_amdgcn_s_setprio(1);
#pragma unroll
        for (int j = 0; j < 4; ++j)
#pragma unroll
            for (int i = 0; i < 4; ++i)
                acc[i][j] = __builtin_amdgcn_mfma_f32_16x16x32_bf16(a0[i], b0[j], acc[i][j], 0, 0, 0);
#pragma unroll
        for (int j = 0; j < 4; ++j)
#pragma unroll
            for (int i = 0; i < 4; ++i)
                acc[4 + i][j] = __builtin_amdgcn_mfma_f32_16x16x32_bf16(a1[i], b0[j], acc[4 + i][j], 0, 0, 0);
        __builtin_amdgcn_s_setprio(0);
        // drain this tile's R0,R1 (next tile's kh0 regions); leaves R2,R3 in flight
        asm volatile("s_waitcnt vmcnt(4)" ::: "memory");
        asm volatile("s_barrier" ::: "memory");
        // read-ahead next tile's kh0 fragments
#pragma unroll
        for (int i = 0; i < 4; ++i)
            a0[i] = *reinterpret_cast<const short8*>(&lds[nxt + aro + i * 512]);
#pragma unroll
        for (int j = 0; j < 4; ++j)
            b0[j] = *reinterpret_cast<const short8*>(&lds[nxt + bro + j * 512]);

        // ============ per-n epilogue: dump acc, re-zero, pipeline continues ======
        if ((vt & 15) == 15) {
            const int n0 = n_base + (vt >> 4) * 256;
            float bv[4];
#pragma unroll
            for (int j = 0; j < 4; ++j) bv[j] = bias[n0 + wn + j * 16 + cn];
#pragma unroll
            for (int ai = 0; ai < 8; ++ai) {
                const int row = m0 + wm + (ai >> 2) * 64 + (ai & 3) * 16 + cm4;
#pragma unroll
                for (int j = 0; j < 4; ++j) {
                    const int col = n0 + wn + j * 16 + cn;
#pragma unroll
                    for (int r = 0; r < 4; ++r)
                        store_val(C, (size_t)(row + r) * Nc + col, acc[ai][j][r] + bv[j]);
                }
            }
#pragma unroll
            for (int i = 0; i < 8; ++i)
#pragma unroll
                for (int j = 0; j < 4; ++j)
                    acc[i][j] = (floatx4){0.f, 0.f, 0.f, 0.f};
        }
    }
}

// ---------------- per-token 16-head attention (wave per token) ----------------
#define ROWP 72

__global__ __launch_bounds__(256)
void attn_kernel(const unsigned short* __restrict__ QKV,
                 unsigned short* __restrict__ O)
{
    const int wave = threadIdx.x >> 6;
    const int lane = threadIdx.x & 63;
    const int n = blockIdx.x * 4 + wave;

    __shared__ unsigned short lq[4][16 * ROWP];
    __shared__ unsigned short lk[4][16 * ROWP];
    __shared__ unsigned short lv[4][16 * ROWP];
    __shared__ float lp[4][256];

    {
        const unsigned short* gq = QKV + (size_t)n * 3072;
        const unsigned short* gk = gq + 1024;
        const unsigned short* gv = gq + 2048;
        for (int t = lane; t < 128; t += 64) {
            int r = t >> 3, c = t & 7;
            *reinterpret_cast<short8*>(&lq[wave][r * ROWP + c * 8]) =
                *reinterpret_cast<const short8*>(gq + t * 8);
            *reinterpret_cast<short8*>(&lk[wave][r * ROWP + c * 8]) =
                *reinterpret_cast<const short8*>(gk + t * 8);
            *reinterpret_cast<short8*>(&lv[wave][r * ROWP + c * 8]) =
                *reinterpret_cast<const short8*>(gv + t * 8);
        }
    }
    __syncthreads();

    const int g = lane & 15;
    const int a = lane >> 4;

    float kf[64];
#pragma unroll
    for (int c2 = 0; c2 < 8; ++c2) {
        short8 kv = *reinterpret_cast<const short8*>(&lk[wave][g * ROWP + c2 * 8]);
#pragma unroll
        for (int e = 0; e < 8; ++e) kf[c2 * 8 + e] = bf2f((unsigned short)kv[e]);
    }

#pragma unroll
    for (int i = 0; i < 4; ++i) {
        const int h = i * 4 + a;
        float s = 0.f;
#pragma unroll
        for (int c2 = 0; c2 < 8; ++c2) {
            short8 qv = *reinterpret_cast<const short8*>(&lq[wave][h * ROWP + c2 * 8]);
#pragma unroll
            for (int e = 0; e < 8; ++e)
                s = fmaf(bf2f((unsigned short)qv[e]), kf[c2 * 8 + e], s);
        }
        s *= 0.125f;

        float m = s;
#pragma unroll
        for (int o = 1; o < 16; o <<= 1) m = fmaxf(m, __shfl_xor(m, o, 64));
        float p = expf(s - m);
        float sum = p;
#pragma unroll
        for (int o = 1; o < 16; o <<= 1) sum += __shfl_xor(sum, o, 64);
        lp[wave][h * 16 + g] = p / sum;
    }
    __syncthreads();

    const int h = lane >> 2;
    const int db = (lane & 3) * 16;
    float o[16];
#pragma unroll
    for (int e = 0; e < 16; ++e) o[e] = 0.f;

    for (int g2 = 0; g2 < 16; ++g2) {
        const float pw = lp[wave][h * 16 + g2];
        short8 v0 = *reinterpret_cast<const short8*>(&lv[wave][g2 * ROWP + db]);
        short8 v1 = *reinterpret_cast<const short8*>(&lv[wave][g2 * ROWP + db + 8]);
#pragma unroll
        for (int e = 0; e < 8; ++e) {
            o[e]     = fmaf(pw, bf2f((unsigned short)v0[e]), o[e]);
            o[8 + e] = fmaf(pw, bf2f((unsigned short)v1[e]), o[8 + e]);
        }
    }

    short8 o0, o1;
#pragma unroll
    for (int e = 0; e < 8; ++e) {
        o0[e] = (short)f2bf(o[e]);
        o1[e] = (short)f2bf(o[8 + e]);
    }
    unsigned short* dst = O + (size_t)n * EMB + h * 64 + db;
    *reinterpret_cast<short8*>(dst) = o0;
    *reinterpret_cast<short8*>(dst + 8) = o1;
}

// ---------------- launch ----------------
extern "C" void kernel_launch(void* const* d_in, const int* in_sizes, int n_in,
                              void* d_out, int out_size, void* d_ws, size_t ws_size,
                              hipStream_t stream)
{
    const float* src = (const float*)d_in[0];
    const float* Wq  = (const float*)d_in[1];
    const float* bq  = (const float*)d_in[2];
    const float* Wk  = (const float*)d_in[3];
    const float* bk  = (const float*)d_in[4];
    const float* Wv  = (const float*)d_in[5];
    const float* bv  = (const float*)d_in[6];
    const float* Wo  = (const float*)d_in[7];
    const float* bo  = (const float*)d_in[8];
    float* out = (float*)d_out;

    unsigned short* ws = (unsigned short*)d_ws;
    unsigned short* src_bf = ws;                                      // 16384*1024
    unsigned short* wqkv   = src_bf + (size_t)NTOK * EMB;             // 3*1024*1024 (Wq|Wk|Wv)
    unsigned short* wo_bf  = wqkv + (size_t)3 * EMB * EMB;            // 1024*1024
    unsigned short* qkv    = wo_bf + (size_t)EMB * EMB;               // 16384*3072
    unsigned short* ab     = qkv + (size_t)NTOK * 3 * EMB;            // 16384*1024
    float* bias_cat        = (float*)(ab + (size_t)NTOK * EMB);       // 3072 floats

    cvt_kernel<<<2048, 256, 0, stream>>>(src, src_bf, NTOK * EMB / 4);
    cvt4_kernel<<<2048, 256, 0, stream>>>(Wq, Wk, Wv, Wo, wqkv);  // fills wqkv then wo_bf
    bias_cat_kernel<<<12, 256, 0, stream>>>(bq, bk, bv, bias_cat);

    // fused QKV projection: [16384][3072]; 256 persistent blocks, 3 n-tiles each
    gemm256mn<unsigned short><<<dim3(256), 512, 0, stream>>>(
        src_bf, wqkv, bias_cat, qkv, 3 * EMB, 3);

    attn_kernel<<<NTOK / 4, 256, 0, stream>>>(qkv, ab);

    // output projection: [16384][1024]; 256 blocks, 1 n-tile each
    gemm256mn<float><<<dim3(256), 512, 0, stream>>>(
        ab, wo_bf, bo, out, EMB, 1);
}

// Round 12
// 200.094 us; speedup vs baseline: 1.0055x; 1.0055x over previous
//
#include <hip/hip_runtime.h>
#include <stdint.h>
#include <stddef.h>

#define EMB 1024
#define NTOK 16384

typedef __attribute__((ext_vector_type(8))) short short8;
typedef __attribute__((ext_vector_type(4))) float floatx4;

__device__ __forceinline__ unsigned short f2bf(float f) {
    union { float f; unsigned int u; } v; v.f = f;
    unsigned int u = v.u;
    unsigned int r = (u + 0x7fffu + ((u >> 16) & 1u)) >> 16;
    return (unsigned short)r;
}
__device__ __forceinline__ float bf2f(unsigned short s) {
    union { unsigned int u; float f; } v; v.u = ((unsigned int)s) << 16;
    return v.f;
}

__device__ __forceinline__ void gload16(const void* g, void* l) {
    __builtin_amdgcn_global_load_lds(
        (const __attribute__((address_space(1))) void*)g,
        (__attribute__((address_space(3))) void*)l, 16, 0, 0);
}

// ---------------- fp32 -> bf16 conversion ----------------
__global__ void cvt_kernel(const float* __restrict__ in,
                           unsigned short* __restrict__ out, int n4) {
    int idx = blockIdx.x * blockDim.x + threadIdx.x;
    int stride = gridDim.x * blockDim.x;
    for (int i = idx; i < n4; i += stride) {
        float4 f = reinterpret_cast<const float4*>(in)[i];
        ushort4 o;
        o.x = f2bf(f.x); o.y = f2bf(f.y); o.z = f2bf(f.z); o.w = f2bf(f.w);
        reinterpret_cast<ushort4*>(out)[i] = o;
    }
}

__global__ void cvt4_kernel(const float* __restrict__ s0, const float* __restrict__ s1,
                            const float* __restrict__ s2, const float* __restrict__ s3,
                            unsigned short* __restrict__ out) {
    int idx = blockIdx.x * blockDim.x + threadIdx.x;
    const int total = 4 << 18;
    int stride = gridDim.x * blockDim.x;
    for (int i = idx; i < total; i += stride) {
        int w = i >> 18, r = i & ((1 << 18) - 1);
        const float* s = (w == 0) ? s0 : (w == 1) ? s1 : (w == 2) ? s2 : s3;
        float4 f = reinterpret_cast<const float4*>(s)[r];
        ushort4 o;
        o.x = f2bf(f.x); o.y = f2bf(f.y); o.z = f2bf(f.z); o.w = f2bf(f.w);
        reinterpret_cast<ushort4*>(out)[i] = o;
    }
}

__global__ void bias_cat_kernel(const float* __restrict__ b0,
                                const float* __restrict__ b1,
                                const float* __restrict__ b2,
                                float* __restrict__ out) {
    int i = blockIdx.x * blockDim.x + threadIdx.x;
    float v = (i < 1024) ? b0[i] : (i < 2048 ? b1[i - 1024] : b2[i - 2048]);
    out[i] = v;
}

// ------ 256x256 bf16 GEMM, BK=32, FOUR 32KB LDS buffers, 2-tile-ahead staging ------
// 512 thr (8 waves 2Mx4N, wave tile 128x64), K=1024 -> 32 K-tiles per n-tile.
// Buffer b (b=0..3) at b*16384 elems: A(256x32) at +0, B(256x32) at +8192.
// Granule = 16B (8 bf16); granule slot XOR-swizzled by (row&3); source pre-swizzled.
// Body(t): read 12 frags from buf(t%4) -> stage tile t+2 into buf((t+2)%4) ->
//          32 MFMA -> vmcnt(4) [drains tile t+1's 4 loads, leaves t+2's] -> barrier.
// Prefetch distance = 2 bodies; 4-buffer rotation makes ONE barrier/tile WAR-safe
// (stage target (t+2)%4 never equals any buffer still being read).
// Persistent blocks: each block fixes m-tile, sweeps nt_n n-tiles continuously.
__device__ __forceinline__ void store_val(float* C, size_t idx, float v) { C[idx] = v; }
__device__ __forceinline__ void store_val(unsigned short* C, size_t idx, float v) { C[idx] = f2bf(v); }

template<typename OUT_T>
__global__ __launch_bounds__(512, 1)
void gemm32q(const unsigned short* __restrict__ A,
             const unsigned short* __restrict__ B,
             const float* __restrict__ bias,
             OUT_T* __restrict__ C,
             int Nc, int nt_n)
{
    __shared__ unsigned short lds[65536];  // 4 x 32 KB
    const int K = 1024;                    // hardcoded (all GEMMs here)

    // XCD mapping: grid = 256 = 8 XCD * 8 m * 4 ngrp
    const int bid = blockIdx.x;
    const int x = bid & 7;
    const int w = bid >> 3;
    const int m0 = (x * 8 + (w & 7)) * 256;
    const int n_base = (w >> 3) * nt_n * 256;

    const int tid = threadIdx.x, lane = tid & 63, wid = tid >> 6;
    const int wm = (wid >> 2) * 128, wn = (wid & 3) * 64;
    const int rr = lane & 15, ls = lane >> 4;
    const int swf = ((ls ^ (rr & 3)) << 3);          // frag k-slot (swizzled), elems
    const int arE = (wm + rr) * 32 + swf;            // A frag base within buffer
    const int brE = 8192 + (wn + rr) * 32 + swf;     // B frag base within buffer

    // staging: thread stages granules tid (rows 0-127) and tid+512 (rows 128-255)
    const int rowT = tid >> 2;
    const int colT = (((tid & 3) ^ (rowT & 3)) << 3); // pre-swizzled source col (elems)
    const unsigned short* pA0 = A + (size_t)(m0 + rowT) * K + colT;
    const unsigned short* pB0 = B + (size_t)(n_base + rowT) * K + colT;
    const size_t half  = (size_t)128 * K;            // +128 rows
    const size_t nstep = (size_t)256 * K;            // per n-tile B panel
    const int ldA = tid * 8, ldB = 8192 + tid * 8;

    floatx4 acc[8][4];
#pragma unroll
    for (int i = 0; i < 8; ++i)
#pragma unroll
        for (int j = 0; j < 4; ++j)
            acc[i][j] = (floatx4){0.f, 0.f, 0.f, 0.f};

    const int TOT = nt_n * 32;
    const int cn  = lane & 15;
    const int cm4 = (lane >> 4) * 4;

    // ---- prologue: stage tiles 0 and 1 (both nb=0) ----
    gload16(pA0,          &lds[ldA]);
    gload16(pA0 + half,   &lds[ldA + 4096]);
    gload16(pB0,          &lds[ldB]);
    gload16(pB0 + half,   &lds[ldB + 4096]);
    gload16(pA0 + 32,          &lds[16384 + ldA]);
    gload16(pA0 + half + 32,   &lds[16384 + ldA + 4096]);
    gload16(pB0 + 32,          &lds[16384 + ldB]);
    gload16(pB0 + half + 32,   &lds[16384 + ldB + 4096]);
    asm volatile("s_waitcnt vmcnt(4)" ::: "memory");   // tile 0 landed; tile 1 in flight
    asm volatile("s_barrier" ::: "memory");

#pragma unroll 4
    for (int vt = 0; vt < TOT; ++vt) {
        const int bufr = (vt & 3) * 16384;

        // ---- read 12 frags of tile vt ----
        short8 a[8], b[4];
#pragma unroll
        for (int i = 0; i < 8; ++i)
            a[i] = *reinterpret_cast<const short8*>(&lds[bufr + arE + i * 512]);
#pragma unroll
        for (int j = 0; j < 4; ++j)
            b[j] = *reinterpret_cast<const short8*>(&lds[bufr + brE + j * 512]);

        // ---- stage tile vt+2 into buf((vt+2)%4) ----
        {
            int t2 = vt + 2; if (t2 >= TOT) t2 -= TOT;   // wrap restage, harmless
            const int buf2 = (t2 & 3) * 16384;
            const int kt2  = (t2 & 31) * 32;
            const unsigned short* pBn = pB0 + (size_t)(t2 >> 5) * nstep + kt2;
            gload16(pA0 + kt2,        &lds[buf2 + ldA]);
            gload16(pA0 + half + kt2, &lds[buf2 + ldA + 4096]);
            gload16(pBn,              &lds[buf2 + ldB]);
            gload16(pBn + half,       &lds[buf2 + ldB + 4096]);
        }

        // ---- 32 MFMA (compiler inserts fine lgkmcnt for the frag reads) ----
        __builtin_amdgcn_s_setprio(1);
#pragma unroll
        for (int j = 0; j < 4; ++j)
#pragma unroll
            for (int i = 0; i < 8; ++i)
                acc[i][j] = __builtin_amdgcn_mfma_f32_16x16x32_bf16(a[i], b[j], acc[i][j], 0, 0, 0);
        __builtin_amdgcn_s_setprio(0);

        // ---- sync: tile vt+1 landed (leaves vt+2's 4 loads in flight) ----
        asm volatile("s_waitcnt vmcnt(4)" ::: "memory");
        asm volatile("s_barrier" ::: "memory");

        // ---- per-n epilogue: dump acc, re-zero; pipeline continues ----
        if ((vt & 31) == 31) {
            const int n0 = n_base + (vt >> 5) * 256;
            float bv[4];
#pragma unroll
            for (int j = 0; j < 4; ++j) bv[j] = bias[n0 + wn + j * 16 + cn];
#pragma unroll
            for (int i = 0; i < 8; ++i) {
                const int row = m0 + wm + i * 16 + cm4;
#pragma unroll
                for (int j = 0; j < 4; ++j) {
                    const int col = n0 + wn + j * 16 + cn;
#pragma unroll
                    for (int r = 0; r < 4; ++r)
                        store_val(C, (size_t)(row + r) * Nc + col, acc[i][j][r] + bv[j]);
                }
            }
#pragma unroll
            for (int i = 0; i < 8; ++i)
#pragma unroll
                for (int j = 0; j < 4; ++j)
                    acc[i][j] = (floatx4){0.f, 0.f, 0.f, 0.f};
        }
    }
}

// ---------------- per-token 16-head attention (wave per token) ----------------
#define ROWP 72

__global__ __launch_bounds__(256)
void attn_kernel(const unsigned short* __restrict__ QKV,
                 unsigned short* __restrict__ O)
{
    const int wave = threadIdx.x >> 6;
    const int lane = threadIdx.x & 63;
    const int n = blockIdx.x * 4 + wave;

    __shared__ unsigned short lq[4][16 * ROWP];
    __shared__ unsigned short lk[4][16 * ROWP];
    __shared__ unsigned short lv[4][16 * ROWP];
    __shared__ float lp[4][256];

    {
        const unsigned short* gq = QKV + (size_t)n * 3072;
        const unsigned short* gk = gq + 1024;
        const unsigned short* gv = gq + 2048;
        for (int t = lane; t < 128; t += 64) {
            int r = t >> 3, c = t & 7;
            *reinterpret_cast<short8*>(&lq[wave][r * ROWP + c * 8]) =
                *reinterpret_cast<const short8*>(gq + t * 8);
            *reinterpret_cast<short8*>(&lk[wave][r * ROWP + c * 8]) =
                *reinterpret_cast<const short8*>(gk + t * 8);
            *reinterpret_cast<short8*>(&lv[wave][r * ROWP + c * 8]) =
                *reinterpret_cast<const short8*>(gv + t * 8);
        }
    }
    __syncthreads();

    const int g = lane & 15;
    const int a = lane >> 4;

    float kf[64];
#pragma unroll
    for (int c2 = 0; c2 < 8; ++c2) {
        short8 kv = *reinterpret_cast<const short8*>(&lk[wave][g * ROWP + c2 * 8]);
#pragma unroll
        for (int e = 0; e < 8; ++e) kf[c2 * 8 + e] = bf2f((unsigned short)kv[e]);
    }

#pragma unroll
    for (int i = 0; i < 4; ++i) {
        const int h = i * 4 + a;
        float s = 0.f;
#pragma unroll
        for (int c2 = 0; c2 < 8; ++c2) {
            short8 qv = *reinterpret_cast<const short8*>(&lq[wave][h * ROWP + c2 * 8]);
#pragma unroll
            for (int e = 0; e < 8; ++e)
                s = fmaf(bf2f((unsigned short)qv[e]), kf[c2 * 8 + e], s);
        }
        s *= 0.125f;

        float m = s;
#pragma unroll
        for (int o = 1; o < 16; o <<= 1) m = fmaxf(m, __shfl_xor(m, o, 64));
        float p = expf(s - m);
        float sum = p;
#pragma unroll
        for (int o = 1; o < 16; o <<= 1) sum += __shfl_xor(sum, o, 64);
        lp[wave][h * 16 + g] = p / sum;
    }
    __syncthreads();

    const int h = lane >> 2;
    const int db = (lane & 3) * 16;
    float o[16];
#pragma unroll
    for (int e = 0; e < 16; ++e) o[e] = 0.f;

    for (int g2 = 0; g2 < 16; ++g2) {
        const float pw = lp[wave][h * 16 + g2];
        short8 v0 = *reinterpret_cast<const short8*>(&lv[wave][g2 * ROWP + db]);
        short8 v1 = *reinterpret_cast<const short8*>(&lv[wave][g2 * ROWP + db + 8]);
#pragma unroll
        for (int e = 0; e < 8; ++e) {
            o[e]     = fmaf(pw, bf2f((unsigned short)v0[e]), o[e]);
            o[8 + e] = fmaf(pw, bf2f((unsigned short)v1[e]), o[8 + e]);
        }
    }

    short8 o0, o1;
#pragma unroll
    for (int e = 0; e < 8; ++e) {
        o0[e] = (short)f2bf(o[e]);
        o1[e] = (short)f2bf(o[8 + e]);
    }
    unsigned short* dst = O + (size_t)n * EMB + h * 64 + db;
    *reinterpret_cast<short8*>(dst) = o0;
    *reinterpret_cast<short8*>(dst + 8) = o1;
}

// ---------------- launch ----------------
extern "C" void kernel_launch(void* const* d_in, const int* in_sizes, int n_in,
                              void* d_out, int out_size, void* d_ws, size_t ws_size,
                              hipStream_t stream)
{
    const float* src = (const float*)d_in[0];
    const float* Wq  = (const float*)d_in[1];
    const float* bq  = (const float*)d_in[2];
    const float* Wk  = (const float*)d_in[3];
    const float* bk  = (const float*)d_in[4];
    const float* Wv  = (const float*)d_in[5];
    const float* bv  = (const float*)d_in[6];
    const float* Wo  = (const float*)d_in[7];
    const float* bo  = (const float*)d_in[8];
    float* out = (float*)d_out;

    unsigned short* ws = (unsigned short*)d_ws;
    unsigned short* src_bf = ws;                                      // 16384*1024
    unsigned short* wqkv   = src_bf + (size_t)NTOK * EMB;             // 3*1024*1024 (Wq|Wk|Wv)
    unsigned short* wo_bf  = wqkv + (size_t)3 * EMB * EMB;            // 1024*1024
    unsigned short* qkv    = wo_bf + (size_t)EMB * EMB;               // 16384*3072
    unsigned short* ab     = qkv + (size_t)NTOK * 3 * EMB;            // 16384*1024
    float* bias_cat        = (float*)(ab + (size_t)NTOK * EMB);       // 3072 floats

    cvt_kernel<<<2048, 256, 0, stream>>>(src, src_bf, NTOK * EMB / 4);
    cvt4_kernel<<<2048, 256, 0, stream>>>(Wq, Wk, Wv, Wo, wqkv);  // fills wqkv then wo_bf
    bias_cat_kernel<<<12, 256, 0, stream>>>(bq, bk, bv, bias_cat);

    // fused QKV projection: [16384][3072]; 256 persistent blocks, 3 n-tiles each
    gemm32q<unsigned short><<<dim3(256), 512, 0, stream>>>(
        src_bf, wqkv, bias_cat, qkv, 3 * EMB, 3);

    attn_kernel<<<NTOK / 4, 256, 0, stream>>>(qkv, ab);

    // output projection: [16384][1024]; 256 blocks, 1 n-tile each
    gemm32q<float><<<dim3(256), 512, 0, stream>>>(
        ab, wo_bf, bo, out, EMB, 1);
}